// Round 5
// baseline (337.769 us; speedup 1.0000x reference)
//
#include <hip/hip_runtime.h>

// Problem constants
#define BATCH   4
#define SEQ     4096
#define DMODEL  1024
#define HDIM    120
#define NPAD    128                    // HD padded to 128 for clean K=4x32 MFMA loop
#define ROWS_TOTAL (BATCH * SEQ)       // 16384

typedef float f32x4 __attribute__((ext_vector_type(4)));
typedef short s16x8 __attribute__((ext_vector_type(8)));

static __device__ __forceinline__ unsigned short f2bf(float f) {
    unsigned u = __float_as_uint(f);
    u += 0x7FFFu + ((u >> 16) & 1u);   // round-to-nearest-even
    return (unsigned short)(u >> 16);
}

static __device__ __forceinline__ s16x8 pack2x4(f32x4 lo, f32x4 hi) {
    s16x8 r;
#pragma unroll
    for (int i = 0; i < 4; ++i) r[i] = (short)f2bf(lo[i]);
#pragma unroll
    for (int i = 0; i < 4; ++i) r[4 + i] = (short)f2bf(hi[i]);
    return r;
}

// ---------------------------------------------------------------------------
// Kernel A (unchanged): context = query @ Wq^T + bq, *wt, row-L2-normalized
// -> ctx bf16 [16384][128] (cols 120..127 zero).
// ---------------------------------------------------------------------------
struct RawAB { f32x4 a[2]; f32x4 b[2][2]; };

__global__ __launch_bounds__(512)
void ctx_norm_kernel(const float* __restrict__ query,
                     const float* __restrict__ Wq,
                     const float* __restrict__ bq,
                     const float* __restrict__ wt,
                     unsigned short* __restrict__ ctx)
{
    __shared__ float lsq[32 * 4];

    const int tid  = threadIdx.x;
    const int lane = tid & 63;
    const int wv   = tid >> 6;
    const int wr   = wv & 1;
    const int wc   = wv >> 1;
    const int l15  = lane & 15;
    const int l4   = lane >> 4;
    const int row0 = blockIdx.x * 32;

    const float* aptr = query + (size_t)(row0 + wr * 16 + l15) * DMODEL + l4 * 8;
    const int c0 = wc * 32 + l15;
    const int c1 = c0 + 16;
    const float* bptr0 = Wq + (size_t)(c0 < HDIM ? c0 : HDIM - 1) * DMODEL + l4 * 8;
    const float* bptr1 = Wq + (size_t)(c1 < HDIM ? c1 : HDIM - 1) * DMODEL + l4 * 8;

    f32x4 acc[2];
#pragma unroll
    for (int n = 0; n < 2; ++n) acc[n] = (f32x4){0.f, 0.f, 0.f, 0.f};

    auto load_raw = [&](RawAB& r, int ks) {
        const int k0 = ks * 32;
        r.a[0] = *(const f32x4*)(aptr + k0);
        r.a[1] = *(const f32x4*)(aptr + k0 + 4);
        r.b[0][0] = *(const f32x4*)(bptr0 + k0);
        r.b[0][1] = *(const f32x4*)(bptr0 + k0 + 4);
        r.b[1][0] = *(const f32x4*)(bptr1 + k0);
        r.b[1][1] = *(const f32x4*)(bptr1 + k0 + 4);
    };
    auto compute = [&](const RawAB& r) {
        const s16x8 a = pack2x4(r.a[0], r.a[1]);
#pragma unroll
        for (int n = 0; n < 2; ++n) {
            const s16x8 bfr = pack2x4(r.b[n][0], r.b[n][1]);
            acc[n] = __builtin_amdgcn_mfma_f32_16x16x32_bf16(a, bfr, acc[n], 0, 0, 0);
        }
    };

    RawAB r0, r1;
    load_raw(r0, 0);
    for (int ks = 0; ks < 32; ks += 2) {
        load_raw(r1, ks + 1 < 32 ? ks + 1 : 31);
        compute(r0);
        load_raw(r0, ks + 2 < 32 ? ks + 2 : 31);
        compute(r1);
    }

    float sumsq[4] = {0.f, 0.f, 0.f, 0.f};
#pragma unroll
    for (int n = 0; n < 2; ++n) {
        const int col = wc * 32 + n * 16 + l15;
        const float bqv = (col < HDIM) ? bq[col] : 0.f;
        const float wvv = (col < HDIM) ? wt[col] : 0.f;
#pragma unroll
        for (int r = 0; r < 4; ++r) {
            const float v = (acc[n][r] + bqv) * wvv;
            acc[n][r] = v;
            sumsq[r] += v * v;
        }
    }
#pragma unroll
    for (int r = 0; r < 4; ++r) {
        float s = sumsq[r];
        s += __shfl_xor(s, 1);
        s += __shfl_xor(s, 2);
        s += __shfl_xor(s, 4);
        s += __shfl_xor(s, 8);
        sumsq[r] = s;
    }
    if (l15 == 0) {
#pragma unroll
        for (int r = 0; r < 4; ++r)
            lsq[(wr * 16 + l4 * 4 + r) * 4 + wc] = sumsq[r];
    }
    __syncthreads();
#pragma unroll
    for (int r = 0; r < 4; ++r) {
        const int lr = wr * 16 + l4 * 4 + r;
        const float s = lsq[lr * 4 + 0] + lsq[lr * 4 + 1] + lsq[lr * 4 + 2] + lsq[lr * 4 + 3];
        const float rinv = 1.f / fmaxf(sqrtf(s), 1e-12f);
        const size_t row = (size_t)(row0 + lr);
#pragma unroll
        for (int n = 0; n < 2; ++n)
            ctx[row * NPAD + wc * 32 + n * 16 + l15] = f2bf(acc[n][r] * rinv);
    }
}

// ---------------------------------------------------------------------------
// Kernel B1: rowsum. Pure GEMM + exp + reduce, ZERO stores in the hot loop ->
// ctx stays L2-clean, loads are L2 hits, no store-drain in the vmcnt FIFO.
// 1024 blocks x 512 thr = 8192 waves; VGPR <= 64 (launch_bounds 8/EU) ->
// 8 waves/SIMD. Block = 16 rows x 4096 cols (8 waves x 512-col strips).
// Writes rinv[row] = 1/rowsum.
// ---------------------------------------------------------------------------
__global__ __launch_bounds__(512, 8)
void rowsum_kernel(const unsigned short* __restrict__ ctx,
                   float* __restrict__ rinv)
{
    __shared__ float lsum[16 * 8];

    const int tid  = threadIdx.x;
    const int lane = tid & 63;
    const int cg   = tid >> 6;          // col-group 0..7 (512 cols)
    const int l15  = lane & 15;
    const int l4   = lane >> 4;

    const int rg   = blockIdx.x;        // row-group 0..1023 (16 rows each)
    const int b    = rg >> 8;           // 256 row-groups per batch
    const int row0 = (rg & 255) * 16;
    const unsigned short* cb = ctx + (size_t)b * SEQ * NPAD;

    s16x8 afrag[4];
    {
        const unsigned short* ap = cb + (size_t)(row0 + l15) * NPAD + l4 * 8;
#pragma unroll
        for (int ks = 0; ks < 4; ++ks) afrag[ks] = *(const s16x8*)(ap + ks * 32);
    }

    const unsigned short* bbase = cb + (size_t)(cg * 512 + l15) * NPAD + l4 * 8;
    float rowsum[4] = {0.f, 0.f, 0.f, 0.f};

    s16x8 bc[4], bn[4];
    auto loadB = [&](s16x8* bf, int t) {
        const unsigned short* bp = bbase + (size_t)t * (16 * NPAD);
#pragma unroll
        for (int ks = 0; ks < 4; ++ks) bf[ks] = *(const s16x8*)(bp + ks * 32);
    };
    auto accum = [&](const s16x8* bf) {
        f32x4 acc = (f32x4){0.f, 0.f, 0.f, 0.f};
#pragma unroll
        for (int ks = 0; ks < 4; ++ks)
            acc = __builtin_amdgcn_mfma_f32_16x16x32_bf16(afrag[ks], bf[ks], acc, 0, 0, 0);
#pragma unroll
        for (int j = 0; j < 4; ++j) rowsum[j] += __expf(acc[j]);
    };

    loadB(bc, 0);
    for (int t = 0; t < 32; t += 2) {
        loadB(bn, t + 1);
        accum(bc);
        loadB(bc, t + 2 < 32 ? t + 2 : 31);
        accum(bn);
    }

#pragma unroll
    for (int j = 0; j < 4; ++j) {
        float s = rowsum[j];
        s += __shfl_xor(s, 1);
        s += __shfl_xor(s, 2);
        s += __shfl_xor(s, 4);
        s += __shfl_xor(s, 8);
        rowsum[j] = s;
    }
    if (l15 == 0) {
#pragma unroll
        for (int j = 0; j < 4; ++j)
            lsum[(l4 * 4 + j) * 8 + cg] = rowsum[j];
    }
    __syncthreads();
    if (tid < 16) {
        float s = 0.f;
#pragma unroll
        for (int w = 0; w < 8; ++w) s += lsum[tid * 8 + w];
        rinv[rg * 16 + tid] = 1.f / s;
    }
}

// ---------------------------------------------------------------------------
// Kernel B2: writer. rowsums are precomputed -> every wave fully independent:
// 16 rows x 256 cols per wave, 4096 blocks x 256 thr = 16384 waves, VGPR ~52
// (single-buffered B) -> 8 waves/SIMD. exp(s)*rinv, NT stores.
// ---------------------------------------------------------------------------
__global__ __launch_bounds__(256, 8)
void write_kernel(const unsigned short* __restrict__ ctx,
                  const float* __restrict__ rinv,
                  float* __restrict__ out)
{
    const int tid  = threadIdx.x;
    const int lane = tid & 63;
    const int wv   = tid >> 6;          // 0..3
    const int l15  = lane & 15;
    const int l4   = lane >> 4;

    const int wid  = blockIdx.x * 4 + wv;   // 0..16383
    const int rg   = wid >> 4;              // row-group 0..1023
    const int cs   = wid & 15;              // col-strip 0..15 (256 cols)
    const int b    = rg >> 8;
    const int row0 = (rg & 255) * 16;
    const int col0 = cs * 256;
    const unsigned short* cb = ctx + (size_t)b * SEQ * NPAD;

    s16x8 afrag[4];
    {
        const unsigned short* ap = cb + (size_t)(row0 + l15) * NPAD + l4 * 8;
#pragma unroll
        for (int ks = 0; ks < 4; ++ks) afrag[ks] = *(const s16x8*)(ap + ks * 32);
    }
    const f32x4 rv4 = *(const f32x4*)(rinv + rg * 16 + l4 * 4);

    float* ob = out + ((size_t)b * SEQ + row0) * SEQ;

#pragma unroll 2
    for (int t = 0; t < 16; ++t) {
        const unsigned short* bp = cb + (size_t)(col0 + t * 16 + l15) * NPAD + l4 * 8;
        s16x8 bf[4];
#pragma unroll
        for (int ks = 0; ks < 4; ++ks) bf[ks] = *(const s16x8*)(bp + ks * 32);
        f32x4 acc = (f32x4){0.f, 0.f, 0.f, 0.f};
#pragma unroll
        for (int ks = 0; ks < 4; ++ks)
            acc = __builtin_amdgcn_mfma_f32_16x16x32_bf16(afrag[ks], bf[ks], acc, 0, 0, 0);
        const int col = col0 + t * 16 + l15;
#pragma unroll
        for (int j = 0; j < 4; ++j)
            __builtin_nontemporal_store(__expf(acc[j]) * rv4[j],
                                        &ob[(size_t)(l4 * 4 + j) * SEQ + col]);
    }
}

extern "C" void kernel_launch(void* const* d_in, const int* in_sizes, int n_in,
                              void* d_out, int out_size, void* d_ws, size_t ws_size,
                              hipStream_t stream)
{
    const float* query = (const float*)d_in[0];
    // d_in[1] = key (unused by the forward)
    const float* Wq    = (const float*)d_in[2];
    const float* bq    = (const float*)d_in[3];
    const float* wt    = (const float*)d_in[4];
    float* out = (float*)d_out;
    unsigned short* ctx = (unsigned short*)d_ws;                   // 4 MiB
    float* rinv = (float*)((char*)d_ws + (size_t)ROWS_TOTAL * NPAD * 2);  // 64 KiB

    ctx_norm_kernel<<<dim3(ROWS_TOTAL / 32), dim3(512), 0, stream>>>(query, Wq, bq, wt, ctx);
    rowsum_kernel<<<dim3(ROWS_TOTAL / 16), dim3(512), 0, stream>>>(ctx, rinv);
    write_kernel<<<dim3(ROWS_TOTAL * 16 / 64), dim3(256), 0, stream>>>(ctx, rinv, out);
}

// Round 6
// 214.101 us; speedup vs baseline: 1.5776x; 1.5776x over previous
//
#include <hip/hip_runtime.h>

// Problem constants
#define BATCH   4
#define SEQ     4096
#define DMODEL  1024
#define HDIM    120
#define NPAD    128
#define ROWS_TOTAL (BATCH * SEQ)       // 16384
#define TPB     256                    // 16-row tiles per batch (SEQ/16)

typedef float f32x4 __attribute__((ext_vector_type(4)));
typedef short s16x8 __attribute__((ext_vector_type(8)));

// F layout (fragment-ordered ctx): s16x8 F[b][tile][ks][lane]
//   F[b][t][ks][lane] = ctx[b][t*16 + (lane&15)][ks*32 + (lane>>4)*8 .. +8] (bf16)
// -> every MFMA fragment load is ONE contiguous 1KB wave-load (lane*16B).
#define FRAG_PER_B ((size_t)TPB * 4 * 64)   // 65536 s16x8 units per batch

static __device__ __forceinline__ unsigned short f2bf(float f) {
    unsigned u = __float_as_uint(f);
    u += 0x7FFFu + ((u >> 16) & 1u);   // round-to-nearest-even
    return (unsigned short)(u >> 16);
}

static __device__ __forceinline__ s16x8 pack2x4(f32x4 lo, f32x4 hi) {
    s16x8 r;
#pragma unroll
    for (int i = 0; i < 4; ++i) r[i] = (short)f2bf(lo[i]);
#pragma unroll
    for (int i = 0; i < 4; ++i) r[4 + i] = (short)f2bf(hi[i]);
    return r;
}

// ---------------------------------------------------------------------------
// Kernel A: context = query @ Wq^T + bq, *wt, row-L2-normalized.
// GEMM part unchanged (control); NEW epilogue: LDS bounce -> store ctx in
// fragment order F (contiguous 1KB wave-stores).
// ---------------------------------------------------------------------------
struct RawAB { f32x4 a[2]; f32x4 b[2][2]; };

__global__ __launch_bounds__(512)
void ctx_norm_kernel(const float* __restrict__ query,
                     const float* __restrict__ Wq,
                     const float* __restrict__ bq,
                     const float* __restrict__ wt,
                     s16x8* __restrict__ F)
{
    __shared__ float lsq[32 * 4];
    __shared__ unsigned short lt[32][136];   // normalized bf16 tile, padded stride

    const int tid  = threadIdx.x;
    const int lane = tid & 63;
    const int wv   = tid >> 6;
    const int wr   = wv & 1;
    const int wc   = wv >> 1;
    const int l15  = lane & 15;
    const int l4   = lane >> 4;
    const int row0 = blockIdx.x * 32;

    const float* aptr = query + (size_t)(row0 + wr * 16 + l15) * DMODEL + l4 * 8;
    const int c0 = wc * 32 + l15;
    const int c1 = c0 + 16;
    const float* bptr0 = Wq + (size_t)(c0 < HDIM ? c0 : HDIM - 1) * DMODEL + l4 * 8;
    const float* bptr1 = Wq + (size_t)(c1 < HDIM ? c1 : HDIM - 1) * DMODEL + l4 * 8;

    f32x4 acc[2];
#pragma unroll
    for (int n = 0; n < 2; ++n) acc[n] = (f32x4){0.f, 0.f, 0.f, 0.f};

    auto load_raw = [&](RawAB& r, int ks) {
        const int k0 = ks * 32;
        r.a[0] = *(const f32x4*)(aptr + k0);
        r.a[1] = *(const f32x4*)(aptr + k0 + 4);
        r.b[0][0] = *(const f32x4*)(bptr0 + k0);
        r.b[0][1] = *(const f32x4*)(bptr0 + k0 + 4);
        r.b[1][0] = *(const f32x4*)(bptr1 + k0);
        r.b[1][1] = *(const f32x4*)(bptr1 + k0 + 4);
    };
    auto compute = [&](const RawAB& r) {
        const s16x8 a = pack2x4(r.a[0], r.a[1]);
#pragma unroll
        for (int n = 0; n < 2; ++n) {
            const s16x8 bfr = pack2x4(r.b[n][0], r.b[n][1]);
            acc[n] = __builtin_amdgcn_mfma_f32_16x16x32_bf16(a, bfr, acc[n], 0, 0, 0);
        }
    };

    RawAB r0, r1;
    load_raw(r0, 0);
    for (int ks = 0; ks < 32; ks += 2) {
        load_raw(r1, ks + 1 < 32 ? ks + 1 : 31);
        compute(r0);
        load_raw(r0, ks + 2 < 32 ? ks + 2 : 31);
        compute(r1);
    }

    float sumsq[4] = {0.f, 0.f, 0.f, 0.f};
#pragma unroll
    for (int n = 0; n < 2; ++n) {
        const int col = wc * 32 + n * 16 + l15;
        const float bqv = (col < HDIM) ? bq[col] : 0.f;
        const float wvv = (col < HDIM) ? wt[col] : 0.f;   // 0 zeroes pad cols
#pragma unroll
        for (int r = 0; r < 4; ++r) {
            const float v = (acc[n][r] + bqv) * wvv;
            acc[n][r] = v;
            sumsq[r] += v * v;
        }
    }
#pragma unroll
    for (int r = 0; r < 4; ++r) {
        float s = sumsq[r];
        s += __shfl_xor(s, 1);
        s += __shfl_xor(s, 2);
        s += __shfl_xor(s, 4);
        s += __shfl_xor(s, 8);
        sumsq[r] = s;
    }
    if (l15 == 0) {
#pragma unroll
        for (int r = 0; r < 4; ++r)
            lsq[(wr * 16 + l4 * 4 + r) * 4 + wc] = sumsq[r];
    }
    __syncthreads();
#pragma unroll
    for (int r = 0; r < 4; ++r) {
        const int lr = wr * 16 + l4 * 4 + r;
        const float s = lsq[lr * 4 + 0] + lsq[lr * 4 + 1] + lsq[lr * 4 + 2] + lsq[lr * 4 + 3];
        const float rinv = 1.f / fmaxf(sqrtf(s), 1e-12f);
#pragma unroll
        for (int n = 0; n < 2; ++n)
            lt[lr][wc * 32 + n * 16 + l15] = f2bf(acc[n][r] * rinv);
    }
    __syncthreads();

    // fragment store: wave wv handles (tile tl = wv>>2, ks = wv&3)
    {
        const int tl = wv >> 2;          // 0..1 (two 16-row tiles per block)
        const int ks = wv & 3;
        const s16x8 fr = *(const s16x8*)&lt[tl * 16 + l15][ks * 32 + l4 * 8];
        F[((size_t)(blockIdx.x * 2 + tl) * 4 + ks) * 64 + lane] = fr;   // 1KB contiguous
    }
}

// ---------------------------------------------------------------------------
// Kernel B1: rowsum. acc = mfma(col_frag, row_frag) -> lane holds row r=l15,
// 4 consecutive cols -> rowsum is ONE scalar per lane, reduce across l4 only.
// All fragment loads contiguous (F layout). Zero stores in hot loop.
// 1024 blocks x 512 thr; block = row-tile tr, 8 waves = 512-col strips.
// ---------------------------------------------------------------------------
__global__ __launch_bounds__(512, 8)
void rowsum_kernel(const s16x8* __restrict__ F, float* __restrict__ rinv)
{
    __shared__ float lsum[16][8];

    const int tid  = threadIdx.x;
    const int lane = tid & 63;
    const int cg   = tid >> 6;          // col strip 0..7
    // XCD swizzle: 1024 blocks -> 128 contiguous units per XCD (same batch)
    const int u    = ((blockIdx.x & 7) << 7) | (blockIdx.x >> 3);
    const int b    = u >> 8;
    const int tr   = u & 255;
    const s16x8* Fb = F + (size_t)b * FRAG_PER_B;

    s16x8 rfrag[4];
#pragma unroll
    for (int ks = 0; ks < 4; ++ks) rfrag[ks] = Fb[((size_t)tr * 4 + ks) * 64 + lane];

    const int tc0 = cg * 32;
    s16x8 cf0[4], cf1[4];
    auto loadC = [&](s16x8* cf, int tc) {
        const s16x8* p = Fb + (size_t)tc * 256 + lane;
#pragma unroll
        for (int ks = 0; ks < 4; ++ks) cf[ks] = p[ks * 64];
    };
    float rs = 0.f;
    auto accum = [&](const s16x8* cf) {
        f32x4 acc = (f32x4){0.f, 0.f, 0.f, 0.f};
#pragma unroll
        for (int ks = 0; ks < 4; ++ks)
            acc = __builtin_amdgcn_mfma_f32_16x16x32_bf16(cf[ks], rfrag[ks], acc, 0, 0, 0);
#pragma unroll
        for (int q = 0; q < 4; ++q) rs += __expf(acc[q]);
    };

    loadC(cf0, tc0);
    loadC(cf1, tc0 + 1);
    for (int i = 0; i < 32; i += 2) {
        accum(cf0);
        if (i + 2 < 32) loadC(cf0, tc0 + i + 2);
        accum(cf1);
        if (i + 3 < 32) loadC(cf1, tc0 + i + 3);
    }

    // reduce across l4 groups (same row r=l15)
    rs += __shfl_xor(rs, 16);
    rs += __shfl_xor(rs, 32);
    if (lane < 16) lsum[lane][cg] = rs;
    __syncthreads();
    if (tid < 16) {
        float s = 0.f;
#pragma unroll
        for (int w = 0; w < 8; ++w) s += lsum[tid][w];
        rinv[u * 16 + tid] = 1.f / s;
    }
}

// ---------------------------------------------------------------------------
// Kernel B2: writer. Swapped-operand MFMA: lane -> (row=l15, 4 consecutive
// cols) -> one NT dwordx4 store per tile per lane. Contiguous frag loads,
// 2-tile register prefetch, stores never block loads (younger in FIFO).
// 2048 blocks x 256 thr = 8192 waves; wave = (b, tr, 512-col strip).
// ---------------------------------------------------------------------------
__global__ __launch_bounds__(256, 8)
void write_kernel(const s16x8* __restrict__ F, const float* __restrict__ rinv,
                  float* __restrict__ out)
{
    const int tid  = threadIdx.x;
    const int lane = tid & 63;
    const int wv   = tid >> 6;
    const int l15  = lane & 15;
    const int l4   = lane >> 4;

    // XCD swizzle: 2048 blocks -> 256 contiguous units per XCD
    const int sb   = ((blockIdx.x & 7) << 8) | (blockIdx.x >> 3);
    const int wid  = sb * 4 + wv;       // 0..8191
    const int b    = wid >> 11;
    const int rem  = wid & 2047;
    const int tr   = rem >> 3;          // row-tile 0..255
    const int cs   = rem & 7;           // col strip 0..7
    const s16x8* Fb = F + (size_t)b * FRAG_PER_B;

    s16x8 rfrag[4];
#pragma unroll
    for (int ks = 0; ks < 4; ++ks) rfrag[ks] = Fb[((size_t)tr * 4 + ks) * 64 + lane];
    const float rv = rinv[(b * TPB + tr) * 16 + l15];
    float* ob = out + ((size_t)b * SEQ + tr * 16 + l15) * SEQ;

    const int tc0 = cs * 32;
    s16x8 cf0[4], cf1[4];
    auto loadC = [&](s16x8* cf, int tc) {
        const s16x8* p = Fb + (size_t)tc * 256 + lane;
#pragma unroll
        for (int ks = 0; ks < 4; ++ks) cf[ks] = p[ks * 64];
    };
    auto emit = [&](const s16x8* cf, int tc) {
        f32x4 acc = (f32x4){0.f, 0.f, 0.f, 0.f};
#pragma unroll
        for (int ks = 0; ks < 4; ++ks)
            acc = __builtin_amdgcn_mfma_f32_16x16x32_bf16(cf[ks], rfrag[ks], acc, 0, 0, 0);
        f32x4 p;
#pragma unroll
        for (int q = 0; q < 4; ++q) p[q] = __expf(acc[q]) * rv;
        __builtin_nontemporal_store(p, (f32x4*)(ob + tc * 16 + l4 * 4));
    };

    loadC(cf0, tc0);
    loadC(cf1, tc0 + 1);
    for (int i = 0; i < 32; i += 2) {
        emit(cf0, tc0 + i);
        if (i + 2 < 32) loadC(cf0, tc0 + i + 2);
        emit(cf1, tc0 + i + 1);
        if (i + 3 < 32) loadC(cf1, tc0 + i + 3);
    }
}

extern "C" void kernel_launch(void* const* d_in, const int* in_sizes, int n_in,
                              void* d_out, int out_size, void* d_ws, size_t ws_size,
                              hipStream_t stream)
{
    const float* query = (const float*)d_in[0];
    // d_in[1] = key (unused by the forward)
    const float* Wq    = (const float*)d_in[2];
    const float* bq    = (const float*)d_in[3];
    const float* wt    = (const float*)d_in[4];
    float* out = (float*)d_out;
    s16x8* F    = (s16x8*)d_ws;                                        // 4 MiB
    float* rinv = (float*)((char*)d_ws + (size_t)ROWS_TOTAL * NPAD * 2); // 64 KiB

    ctx_norm_kernel<<<dim3(ROWS_TOTAL / 32), dim3(512), 0, stream>>>(query, Wq, bq, wt, F);
    rowsum_kernel<<<dim3(BATCH * TPB), dim3(512), 0, stream>>>(F, rinv);
    write_kernel<<<dim3(BATCH * TPB * 8 / 4), dim3(256), 0, stream>>>(F, rinv, out);
}

// Round 7
// 195.603 us; speedup vs baseline: 1.7268x; 1.0946x over previous
//
#include <hip/hip_runtime.h>

// Problem constants
#define BATCH   4
#define SEQ     4096
#define DMODEL  1024
#define HDIM    120
#define NPAD    128
#define ROWS_TOTAL (BATCH * SEQ)       // 16384
#define TPB     256                    // 16-row tiles per batch (SEQ/16)

typedef float f32x4 __attribute__((ext_vector_type(4)));
typedef short s16x8 __attribute__((ext_vector_type(8)));

// F layout (fragment-ordered ctx): s16x8 F[b][tile][ks][lane]
//   F[b][t][ks][lane] = ctx_n[b][t*16 + (lane&15)][ks*32 + (lane>>4)*8 .. +8]
// -> every MFMA fragment load is ONE contiguous 1KB wave-load.
#define FRAG_PER_B ((size_t)TPB * 4 * 64)

static __device__ __forceinline__ unsigned short f2bf(float f) {
    unsigned u = __float_as_uint(f);
    u += 0x7FFFu + ((u >> 16) & 1u);   // round-to-nearest-even
    return (unsigned short)(u >> 16);
}

static __device__ __forceinline__ s16x8 pack2x4(f32x4 lo, f32x4 hi) {
    s16x8 r;
#pragma unroll
    for (int i = 0; i < 4; ++i) r[i] = (short)f2bf(lo[i]);
#pragma unroll
    for (int i = 0; i < 4; ++i) r[4 + i] = (short)f2bf(hi[i]);
    return r;
}

// ---------------------------------------------------------------------------
// Kernel A (unchanged from R6): context = query @ Wq^T + bq, *wt, row-L2-
// normalized; epilogue LDS-bounces into fragment-ordered F.
// ---------------------------------------------------------------------------
struct RawAB { f32x4 a[2]; f32x4 b[2][2]; };

__global__ __launch_bounds__(512)
void ctx_norm_kernel(const float* __restrict__ query,
                     const float* __restrict__ Wq,
                     const float* __restrict__ bq,
                     const float* __restrict__ wt,
                     s16x8* __restrict__ F)
{
    __shared__ float lsq[32 * 4];
    __shared__ unsigned short lt[32][136];

    const int tid  = threadIdx.x;
    const int lane = tid & 63;
    const int wv   = tid >> 6;
    const int wr   = wv & 1;
    const int wc   = wv >> 1;
    const int l15  = lane & 15;
    const int l4   = lane >> 4;
    const int row0 = blockIdx.x * 32;

    const float* aptr = query + (size_t)(row0 + wr * 16 + l15) * DMODEL + l4 * 8;
    const int c0 = wc * 32 + l15;
    const int c1 = c0 + 16;
    const float* bptr0 = Wq + (size_t)(c0 < HDIM ? c0 : HDIM - 1) * DMODEL + l4 * 8;
    const float* bptr1 = Wq + (size_t)(c1 < HDIM ? c1 : HDIM - 1) * DMODEL + l4 * 8;

    f32x4 acc[2];
#pragma unroll
    for (int n = 0; n < 2; ++n) acc[n] = (f32x4){0.f, 0.f, 0.f, 0.f};

    auto load_raw = [&](RawAB& r, int ks) {
        const int k0 = ks * 32;
        r.a[0] = *(const f32x4*)(aptr + k0);
        r.a[1] = *(const f32x4*)(aptr + k0 + 4);
        r.b[0][0] = *(const f32x4*)(bptr0 + k0);
        r.b[0][1] = *(const f32x4*)(bptr0 + k0 + 4);
        r.b[1][0] = *(const f32x4*)(bptr1 + k0);
        r.b[1][1] = *(const f32x4*)(bptr1 + k0 + 4);
    };
    auto compute = [&](const RawAB& r) {
        const s16x8 a = pack2x4(r.a[0], r.a[1]);
#pragma unroll
        for (int n = 0; n < 2; ++n) {
            const s16x8 bfr = pack2x4(r.b[n][0], r.b[n][1]);
            acc[n] = __builtin_amdgcn_mfma_f32_16x16x32_bf16(a, bfr, acc[n], 0, 0, 0);
        }
    };

    RawAB r0, r1;
    load_raw(r0, 0);
    for (int ks = 0; ks < 32; ks += 2) {
        load_raw(r1, ks + 1 < 32 ? ks + 1 : 31);
        compute(r0);
        load_raw(r0, ks + 2 < 32 ? ks + 2 : 31);
        compute(r1);
    }

    float sumsq[4] = {0.f, 0.f, 0.f, 0.f};
#pragma unroll
    for (int n = 0; n < 2; ++n) {
        const int col = wc * 32 + n * 16 + l15;
        const float bqv = (col < HDIM) ? bq[col] : 0.f;
        const float wvv = (col < HDIM) ? wt[col] : 0.f;
#pragma unroll
        for (int r = 0; r < 4; ++r) {
            const float v = (acc[n][r] + bqv) * wvv;
            acc[n][r] = v;
            sumsq[r] += v * v;
        }
    }
#pragma unroll
    for (int r = 0; r < 4; ++r) {
        float s = sumsq[r];
        s += __shfl_xor(s, 1);
        s += __shfl_xor(s, 2);
        s += __shfl_xor(s, 4);
        s += __shfl_xor(s, 8);
        sumsq[r] = s;
    }
    if (l15 == 0) {
#pragma unroll
        for (int r = 0; r < 4; ++r)
            lsq[(wr * 16 + l4 * 4 + r) * 4 + wc] = sumsq[r];
    }
    __syncthreads();
#pragma unroll
    for (int r = 0; r < 4; ++r) {
        const int lr = wr * 16 + l4 * 4 + r;
        const float s = lsq[lr * 4 + 0] + lsq[lr * 4 + 1] + lsq[lr * 4 + 2] + lsq[lr * 4 + 3];
        const float rinv = 1.f / fmaxf(sqrtf(s), 1e-12f);
#pragma unroll
        for (int n = 0; n < 2; ++n)
            lt[lr][wc * 32 + n * 16 + l15] = f2bf(acc[n][r] * rinv);
    }
    __syncthreads();
    {
        const int tl = wv >> 2;
        const int ks = wv & 3;
        const s16x8 fr = *(const s16x8*)&lt[tl * 16 + l15][ks * 32 + l4 * 8];
        F[((size_t)(blockIdx.x * 2 + tl) * 4 + ks) * 64 + lane] = fr;
    }
}

// ---------------------------------------------------------------------------
// Kernel B (fused, SINGLE GEMM pass): per wave: 16 rows x 512 cols.
// For each of 32 col-tiles: contiguous frag loads -> 4 MFMA -> exp (f32,
// accumulated into rowsum BEFORE rounding) -> packed bf16 pair stash in
// statically-indexed registers. Then LDS cross-wave rowsum reduce, then
// unpack+scale+NT-store. No recompute, no second pass.
// 1024 blocks x 512 thr (8 waves = 8 col-strips). VGPR budget ~118 <= 128.
// ---------------------------------------------------------------------------
__global__ __launch_bounds__(512, 4)
void gram_fused_kernel(const s16x8* __restrict__ F, float* __restrict__ out)
{
    __shared__ float lsum[16][8];

    const int tid  = threadIdx.x;
    const int lane = tid & 63;
    const int cg   = tid >> 6;          // col strip 0..7 (512 cols)
    const int l15  = lane & 15;
    const int l4   = lane >> 4;

    // XCD swizzle: 1024 blocks -> 128 contiguous row-groups per XCD,
    // each batch confined to 2 XCDs (F_b = 1MB, L2-resident).
    const int u    = ((blockIdx.x & 7) << 7) | (blockIdx.x >> 3);
    const int b    = u >> 8;
    const int tr   = u & 255;           // 16-row tile within batch
    const s16x8* Fb = F + (size_t)b * FRAG_PER_B;

    s16x8 rfrag[4];
#pragma unroll
    for (int ks = 0; ks < 4; ++ks) rfrag[ks] = Fb[((size_t)tr * 4 + ks) * 64 + lane];

    // exp stash: 32 tiles x 2 packed-bf16-pairs, statically indexed (rule #20)
    unsigned ex0[32], ex1[32];
    float rs = 0.f;

#pragma unroll
    for (int t = 0; t < 32; ++t) {
        const int tc = cg * 32 + t;
        const s16x8* p = Fb + (size_t)tc * 256 + lane;
        s16x8 cf[4];
#pragma unroll
        for (int ks = 0; ks < 4; ++ks) cf[ks] = p[ks * 64];
        f32x4 acc = (f32x4){0.f, 0.f, 0.f, 0.f};
#pragma unroll
        for (int ks = 0; ks < 4; ++ks)
            acc = __builtin_amdgcn_mfma_f32_16x16x32_bf16(cf[ks], rfrag[ks], acc, 0, 0, 0);
        float e0 = __expf(acc[0]);
        float e1 = __expf(acc[1]);
        float e2 = __expf(acc[2]);
        float e3 = __expf(acc[3]);
        rs += (e0 + e1) + (e2 + e3);
        ex0[t] = (unsigned)f2bf(e0) | ((unsigned)f2bf(e1) << 16);
        ex1[t] = (unsigned)f2bf(e2) | ((unsigned)f2bf(e3) << 16);
    }

    // rowsum reduce: lanes sharing l15 (same row) are l4 groups -> xor 16,32
    rs += __shfl_xor(rs, 16);
    rs += __shfl_xor(rs, 32);
    if (lane < 16) lsum[lane][cg] = rs;
    __syncthreads();
    float s = 0.f;
#pragma unroll
    for (int w = 0; w < 8; ++w) s += lsum[l15][w];
    const float rv = 1.f / s;

    // write: unpack bf16 pairs, scale, NT dwordx4 store
    float* ob = out + ((size_t)b * SEQ + tr * 16 + l15) * SEQ;
#pragma unroll
    for (int t = 0; t < 32; ++t) {
        const unsigned u0 = ex0[t], u1 = ex1[t];
        f32x4 pv;
        pv[0] = __uint_as_float(u0 << 16) * rv;
        pv[1] = __uint_as_float(u0 & 0xFFFF0000u) * rv;
        pv[2] = __uint_as_float(u1 << 16) * rv;
        pv[3] = __uint_as_float(u1 & 0xFFFF0000u) * rv;
        __builtin_nontemporal_store(pv, (f32x4*)(ob + cg * 512 + t * 16 + l4 * 4));
    }
}

extern "C" void kernel_launch(void* const* d_in, const int* in_sizes, int n_in,
                              void* d_out, int out_size, void* d_ws, size_t ws_size,
                              hipStream_t stream)
{
    const float* query = (const float*)d_in[0];
    // d_in[1] = key (unused by the forward)
    const float* Wq    = (const float*)d_in[2];
    const float* bq    = (const float*)d_in[3];
    const float* wt    = (const float*)d_in[4];
    float* out = (float*)d_out;
    s16x8* F = (s16x8*)d_ws;   // 4 MiB fragment-ordered normalized context

    ctx_norm_kernel<<<dim3(ROWS_TOTAL / 32), dim3(512), 0, stream>>>(query, Wq, bq, wt, F);
    gram_fused_kernel<<<dim3(BATCH * TPB), dim3(512), 0, stream>>>(F, out);
}

// Round 9
// 193.437 us; speedup vs baseline: 1.7461x; 1.0112x over previous
//
#include <hip/hip_runtime.h>

// Problem constants
#define BATCH   4
#define SEQ     4096
#define DMODEL  1024
#define HDIM    120
#define NPAD    128
#define ROWS_TOTAL (BATCH * SEQ)       // 16384
#define TPB     256                    // 16-row tiles per batch (SEQ/16)

typedef float f32x4 __attribute__((ext_vector_type(4)));
typedef short s16x8 __attribute__((ext_vector_type(8)));

// F layout (fragment-ordered ctx): s16x8 F[b][tile][ks][lane]
//   F[b][t][ks][lane] = ctx_n[b][t*16 + (lane&15)][ks*32 + (lane>>4)*8 .. +8]
// -> every MFMA fragment load is ONE contiguous 1KB wave-load.
#define FRAG_PER_B ((size_t)TPB * 4 * 64)

static __device__ __forceinline__ unsigned short f2bf(float f) {
    unsigned u = __float_as_uint(f);
    u += 0x7FFFu + ((u >> 16) & 1u);   // round-to-nearest-even
    return (unsigned short)(u >> 16);
}

static __device__ __forceinline__ s16x8 pack2x4(f32x4 lo, f32x4 hi) {
    s16x8 r;
#pragma unroll
    for (int i = 0; i < 4; ++i) r[i] = (short)f2bf(lo[i]);
#pragma unroll
    for (int i = 0; i < 4; ++i) r[4 + i] = (short)f2bf(hi[i]);
    return r;
}

// ---------------------------------------------------------------------------
// Kernel A (unchanged, control): context = query @ Wq^T + bq, *wt, row-L2-
// normalized; epilogue LDS-bounces into fragment-ordered F.
// ---------------------------------------------------------------------------
struct RawAB { f32x4 a[2]; f32x4 b[2][2]; };

__global__ __launch_bounds__(512)
void ctx_norm_kernel(const float* __restrict__ query,
                     const float* __restrict__ Wq,
                     const float* __restrict__ bq,
                     const float* __restrict__ wt,
                     s16x8* __restrict__ F)
{
    __shared__ float lsq[32 * 4];
    __shared__ unsigned short lt[32][136];

    const int tid  = threadIdx.x;
    const int lane = tid & 63;
    const int wv   = tid >> 6;
    const int wr   = wv & 1;
    const int wc   = wv >> 1;
    const int l15  = lane & 15;
    const int l4   = lane >> 4;
    const int row0 = blockIdx.x * 32;

    const float* aptr = query + (size_t)(row0 + wr * 16 + l15) * DMODEL + l4 * 8;
    const int c0 = wc * 32 + l15;
    const int c1 = c0 + 16;
    const float* bptr0 = Wq + (size_t)(c0 < HDIM ? c0 : HDIM - 1) * DMODEL + l4 * 8;
    const float* bptr1 = Wq + (size_t)(c1 < HDIM ? c1 : HDIM - 1) * DMODEL + l4 * 8;

    f32x4 acc[2];
#pragma unroll
    for (int n = 0; n < 2; ++n) acc[n] = (f32x4){0.f, 0.f, 0.f, 0.f};

    auto load_raw = [&](RawAB& r, int ks) {
        const int k0 = ks * 32;
        r.a[0] = *(const f32x4*)(aptr + k0);
        r.a[1] = *(const f32x4*)(aptr + k0 + 4);
        r.b[0][0] = *(const f32x4*)(bptr0 + k0);
        r.b[0][1] = *(const f32x4*)(bptr0 + k0 + 4);
        r.b[1][0] = *(const f32x4*)(bptr1 + k0);
        r.b[1][1] = *(const f32x4*)(bptr1 + k0 + 4);
    };
    auto compute = [&](const RawAB& r) {
        const s16x8 a = pack2x4(r.a[0], r.a[1]);
#pragma unroll
        for (int n = 0; n < 2; ++n) {
            const s16x8 bfr = pack2x4(r.b[n][0], r.b[n][1]);
            acc[n] = __builtin_amdgcn_mfma_f32_16x16x32_bf16(a, bfr, acc[n], 0, 0, 0);
        }
    };

    RawAB r0, r1;
    load_raw(r0, 0);
    for (int ks = 0; ks < 32; ks += 2) {
        load_raw(r1, ks + 1 < 32 ? ks + 1 : 31);
        compute(r0);
        load_raw(r0, ks + 2 < 32 ? ks + 2 : 31);
        compute(r1);
    }

    float sumsq[4] = {0.f, 0.f, 0.f, 0.f};
#pragma unroll
    for (int n = 0; n < 2; ++n) {
        const int col = wc * 32 + n * 16 + l15;
        const float bqv = (col < HDIM) ? bq[col] : 0.f;
        const float wvv = (col < HDIM) ? wt[col] : 0.f;
#pragma unroll
        for (int r = 0; r < 4; ++r) {
            const float v = (acc[n][r] + bqv) * wvv;
            acc[n][r] = v;
            sumsq[r] += v * v;
        }
    }
#pragma unroll
    for (int r = 0; r < 4; ++r) {
        float s = sumsq[r];
        s += __shfl_xor(s, 1);
        s += __shfl_xor(s, 2);
        s += __shfl_xor(s, 4);
        s += __shfl_xor(s, 8);
        sumsq[r] = s;
    }
    if (l15 == 0) {
#pragma unroll
        for (int r = 0; r < 4; ++r)
            lsq[(wr * 16 + l4 * 4 + r) * 4 + wc] = sumsq[r];
    }
    __syncthreads();
#pragma unroll
    for (int r = 0; r < 4; ++r) {
        const int lr = wr * 16 + l4 * 4 + r;
        const float s = lsq[lr * 4 + 0] + lsq[lr * 4 + 1] + lsq[lr * 4 + 2] + lsq[lr * 4 + 3];
        const float rinv = 1.f / fmaxf(sqrtf(s), 1e-12f);
#pragma unroll
        for (int n = 0; n < 2; ++n)
            lt[lr][wc * 32 + n * 16 + l15] = f2bf(acc[n][r] * rinv);
    }
    __syncthreads();
    {
        const int tl = wv >> 2;
        const int ks = wv & 3;
        const s16x8 fr = *(const s16x8*)&lt[tl * 16 + l15][ks * 32 + l4 * 8];
        F[((size_t)(blockIdx.x * 2 + tl) * 4 + ks) * 64 + lane] = fr;
    }
}

// ---------------------------------------------------------------------------
// Kernel B (fused single pass, v3 FIXED GRID): 1024 blocks x 1024 thr.
// Block = ONE 16-row tile x 4096 cols; 16 waves = 16 x 256-col strips.
// Per wave: 16 col-tiles, DEPTH-3 named-register prefetch (cA/cB/cC) so each
// tile's load is issued ~2 compute-slots before use. Stash 32 VGPR (packed
// bf16 pairs), rfrag 16, cf 48, total ~111 < 128 cap -> 4 waves/SIMD.
// ---------------------------------------------------------------------------
#define LOADT(dst, t) { const s16x8* _p = base + (size_t)(t) * 256;            \
    dst[0] = _p[0]; dst[1] = _p[64]; dst[2] = _p[128]; dst[3] = _p[192]; }

#define COMPT(src, t) { f32x4 _a = (f32x4){0.f, 0.f, 0.f, 0.f};                \
    _a = __builtin_amdgcn_mfma_f32_16x16x32_bf16(src[0], rfrag[0], _a, 0,0,0); \
    _a = __builtin_amdgcn_mfma_f32_16x16x32_bf16(src[1], rfrag[1], _a, 0,0,0); \
    _a = __builtin_amdgcn_mfma_f32_16x16x32_bf16(src[2], rfrag[2], _a, 0,0,0); \
    _a = __builtin_amdgcn_mfma_f32_16x16x32_bf16(src[3], rfrag[3], _a, 0,0,0); \
    const float _e0 = __expf(_a[0]), _e1 = __expf(_a[1]);                      \
    const float _e2 = __expf(_a[2]), _e3 = __expf(_a[3]);                      \
    rs += (_e0 + _e1) + (_e2 + _e3);                                           \
    ex0[t] = (unsigned)f2bf(_e0) | ((unsigned)f2bf(_e1) << 16);                \
    ex1[t] = (unsigned)f2bf(_e2) | ((unsigned)f2bf(_e3) << 16); }

__global__ __launch_bounds__(1024, 4)
void gram_fused_kernel(const s16x8* __restrict__ F, float* __restrict__ out)
{
    __shared__ float lsum[16][16];

    const int tid  = threadIdx.x;
    const int lane = tid & 63;
    const int cg   = tid >> 6;          // col strip 0..15 (256 cols)
    const int l15  = lane & 15;
    const int l4   = lane >> 4;

    // XCD swizzle (bijective on 1024 blocks): 128 contiguous row-tiles/XCD;
    // each batch (1MB of F) confined to 2 XCDs' L2.
    const int u    = ((blockIdx.x & 7) << 7) | (blockIdx.x >> 3);
    const int b    = u >> 8;
    const int tr   = u & 255;           // 16-row tile within batch
    const s16x8* Fb = F + (size_t)b * FRAG_PER_B;

    s16x8 rfrag[4];
#pragma unroll
    for (int ks = 0; ks < 4; ++ks) rfrag[ks] = Fb[((size_t)tr * 4 + ks) * 64 + lane];

    const s16x8* base = Fb + (size_t)(cg * 16) * 256 + lane;

    unsigned ex0[16], ex1[16];
    float rs = 0.f;
    s16x8 cA[4], cB[4], cC[4];

    LOADT(cA, 0)
    LOADT(cB, 1)
    LOADT(cC, 2)
#pragma unroll
    for (int i = 0; i < 6; ++i) {
        const int t = i * 3;
        { COMPT(cA, t)           if (t + 3 < 16) LOADT(cA, t + 3) }
        if (t + 1 < 16) { COMPT(cB, t + 1) if (t + 4 < 16) LOADT(cB, t + 4) }
        if (t + 2 < 16) { COMPT(cC, t + 2) if (t + 5 < 16) LOADT(cC, t + 5) }
    }

    // rowsum: l4 groups hold partial sums of the same row l15
    rs += __shfl_xor(rs, 16);
    rs += __shfl_xor(rs, 32);
    if (lane < 16) lsum[lane][cg] = rs;
    __syncthreads();
    float s = 0.f;
#pragma unroll
    for (int w = 0; w < 16; ++w) s += lsum[l15][w];
    const float rv = 1.f / s;

    // write: unpack bf16 pairs, scale, NT dwordx4 store
    float* ob = out + ((size_t)b * SEQ + tr * 16 + l15) * SEQ + cg * 256;
#pragma unroll
    for (int t = 0; t < 16; ++t) {
        const unsigned u0 = ex0[t], u1 = ex1[t];
        f32x4 pv;
        pv[0] = __uint_as_float(u0 << 16) * rv;
        pv[1] = __uint_as_float(u0 & 0xFFFF0000u) * rv;
        pv[2] = __uint_as_float(u1 << 16) * rv;
        pv[3] = __uint_as_float(u1 & 0xFFFF0000u) * rv;
        __builtin_nontemporal_store(pv, (f32x4*)(ob + t * 16 + l4 * 4));
    }
}

extern "C" void kernel_launch(void* const* d_in, const int* in_sizes, int n_in,
                              void* d_out, int out_size, void* d_ws, size_t ws_size,
                              hipStream_t stream)
{
    const float* query = (const float*)d_in[0];
    // d_in[1] = key (unused by the forward)
    const float* Wq    = (const float*)d_in[2];
    const float* bq    = (const float*)d_in[3];
    const float* wt    = (const float*)d_in[4];
    float* out = (float*)d_out;
    s16x8* F = (s16x8*)d_ws;   // 4 MiB fragment-ordered normalized context

    ctx_norm_kernel<<<dim3(ROWS_TOTAL / 32), dim3(512), 0, stream>>>(query, Wq, bq, wt, F);
    // ONE block per 16-row tile: grid MUST be BATCH*TPB = 1024 (R8 bug: /4)
    gram_fused_kernel<<<dim3(BATCH * TPB), dim3(1024), 0, stream>>>(F, out);
}

// Round 11
// 109.679 us; speedup vs baseline: 3.0796x; 1.7637x over previous
//
#include <hip/hip_runtime.h>
#include <hip/hip_fp16.h>

// Problem constants
#define BATCH   4
#define SEQ     4096
#define DMODEL  1024
#define HDIM    120
#define NPAD    128
#define ROWS_TOTAL (BATCH * SEQ)       // 16384
#define TPB     256                    // 16-row tiles per batch (SEQ/16)

typedef float f32x4 __attribute__((ext_vector_type(4)));
typedef short s16x8 __attribute__((ext_vector_type(8)));

// F layout (fragment-ordered ctx): s16x8 F[global_tile][ks][lane]
//   = ctx_n[tile*16 + (lane&15)][ks*32 + (lane>>4)*8 .. +8]  (bf16)
#define FRAG_PER_B ((size_t)TPB * 4 * 64)
// WF layout (fragment-ordered Wq*wt, bf16): s16x8 WF[(ct*32+ks)*64 + lane]
//   = (Wq*wt)[ct*16 + (lane&15)][ks*32 + (lane>>4)*8 .. +8], zero for col>=120

static __device__ __forceinline__ unsigned short f2bf(float f) {
    unsigned u = __float_as_uint(f);
    u += 0x7FFFu + ((u >> 16) & 1u);   // RNE
    return (unsigned short)(u >> 16);
}
static __device__ __forceinline__ s16x8 pack2x4(f32x4 lo, f32x4 hi) {
    s16x8 r;
#pragma unroll
    for (int i = 0; i < 4; ++i) r[i] = (short)f2bf(lo[i]);
#pragma unroll
    for (int i = 0; i < 4; ++i) r[4 + i] = (short)f2bf(hi[i]);
    return r;
}

// ---------------------------------------------------------------------------
// Kernel W: Wq [120][1024] f32 -> WF fragment-ordered bf16, wt folded in.
// ---------------------------------------------------------------------------
__global__ __launch_bounds__(64)
void wq_frag_kernel(const float* __restrict__ Wq, const float* __restrict__ wt,
                    s16x8* __restrict__ WF)
{
    const int lane = threadIdx.x;
    const int l15  = lane & 15;
    const int l4   = lane >> 4;
    const int ct   = blockIdx.x >> 5;
    const int ks   = blockIdx.x & 31;
    const int col  = ct * 16 + l15;

    f32x4 lo = (f32x4){0.f,0.f,0.f,0.f}, hi = lo;
    if (col < HDIM) {
        const float w = wt[col];
        const float* src = Wq + (size_t)col * DMODEL + ks * 32 + l4 * 8;
        lo = *(const f32x4*)(src);
        hi = *(const f32x4*)(src + 4);
#pragma unroll
        for (int i = 0; i < 4; ++i) { lo[i] *= w; hi[i] *= w; }
    }
    WF[((size_t)(ct * 32 + ks)) * 64 + lane] = pack2x4(lo, hi);
}

// ---------------------------------------------------------------------------
// Kernel A v2: context = query @ (Wq*wt)^T + bq*wt, row-L2-normalized -> F.
// 256 blocks x 512 thr (8 waves = 4 row-groups x 2 col-halves), 64 rows/block.
// Query staged via FULL-LINE f32x4 loads -> bf16 LDS (double-buffered, one
// barrier/K-step, register prefetch). B-frags: contiguous 1KB loads from WF.
// ---------------------------------------------------------------------------
__global__ __launch_bounds__(512)
void ctx_norm_kernel(const float* __restrict__ query,
                     const s16x8* __restrict__ WF,
                     const float* __restrict__ bq,
                     const float* __restrict__ wt,
                     s16x8* __restrict__ F)
{
    __shared__ unsigned short lA[2][64 * 40];   // 40-short row stride (2-way free)
    __shared__ float lsq[64][2];
    __shared__ unsigned short lt[64][136];      // 16B-aligned stride, 2-way free

    const int tid  = threadIdx.x;
    const int lane = tid & 63;
    const int wv   = tid >> 6;          // 0..7
    const int wr   = wv & 3;            // row group (16 rows)
    const int wc   = wv >> 2;           // col half (64 cols = 4 tiles)
    const int l15  = lane & 15;
    const int l4   = lane >> 4;
    const int row0 = blockIdx.x * 64;

    const int arow = tid >> 3, achk = tid & 7;  // staging: row 0..63, 4-float chunk
    const float* aload = query + (size_t)(row0 + arow) * DMODEL + achk * 4;

    f32x4 acc[4];
#pragma unroll
    for (int n = 0; n < 4; ++n) acc[n] = (f32x4){0.f,0.f,0.f,0.f};

    f32x4 pr = *(const f32x4*)(aload);          // ks=0 prefetch
    {   // stage ks=0 into buf 0
        const unsigned u0 = (unsigned)f2bf(pr[0]) | ((unsigned)f2bf(pr[1]) << 16);
        const unsigned u1 = (unsigned)f2bf(pr[2]) | ((unsigned)f2bf(pr[3]) << 16);
        *(uint2*)&lA[0][arow * 40 + achk * 4] = make_uint2(u0, u1);
    }

    for (int ks = 0; ks < 32; ++ks) {
        __syncthreads();                         // lA[ks&1] staged; prev reads done
        if (ks + 1 < 32) pr = *(const f32x4*)(aload + (ks + 1) * 32);
        const int buf = ks & 1;
        const s16x8 a = *(const s16x8*)&lA[buf][(wr * 16 + l15) * 40 + l4 * 8];
#pragma unroll
        for (int n = 0; n < 4; ++n) {
            const s16x8 bfr = WF[((size_t)((wc * 4 + n) * 32 + ks)) * 64 + lane];
            acc[n] = __builtin_amdgcn_mfma_f32_16x16x32_bf16(a, bfr, acc[n], 0, 0, 0);
        }
        if (ks + 1 < 32) {
            const unsigned u0 = (unsigned)f2bf(pr[0]) | ((unsigned)f2bf(pr[1]) << 16);
            const unsigned u1 = (unsigned)f2bf(pr[2]) | ((unsigned)f2bf(pr[3]) << 16);
            *(uint2*)&lA[buf ^ 1][arow * 40 + achk * 4] = make_uint2(u0, u1);
        }
    }

    // epilogue: + bq*wt, row L2-norm (reduce over l15, then col halves)
    float sumsq[4] = {0.f,0.f,0.f,0.f};
#pragma unroll
    for (int n = 0; n < 4; ++n) {
        const int col = wc * 64 + n * 16 + l15;
        const float bqv = (col < HDIM) ? bq[col] * wt[col] : 0.f;
#pragma unroll
        for (int r = 0; r < 4; ++r) {
            const float v = acc[n][r] + bqv;
            acc[n][r] = v;
            sumsq[r] += v * v;
        }
    }
#pragma unroll
    for (int r = 0; r < 4; ++r) {
        float s = sumsq[r];
        s += __shfl_xor(s, 1);
        s += __shfl_xor(s, 2);
        s += __shfl_xor(s, 4);
        s += __shfl_xor(s, 8);
        sumsq[r] = s;
    }
    if (l15 == 0) {
#pragma unroll
        for (int r = 0; r < 4; ++r)
            lsq[wr * 16 + l4 * 4 + r][wc] = sumsq[r];
    }
    __syncthreads();
#pragma unroll
    for (int r = 0; r < 4; ++r) {
        const int lr = wr * 16 + l4 * 4 + r;
        const float s = lsq[lr][0] + lsq[lr][1];
        const float rinv = 1.f / fmaxf(sqrtf(s), 1e-12f);
#pragma unroll
        for (int n = 0; n < 4; ++n)
            lt[lr][wc * 64 + n * 16 + l15] = f2bf(acc[n][r] * rinv);
    }
    __syncthreads();
    // fragment store: 16 frags (4 tiles x 4 ks-groups), 2 per wave, 1KB each
#pragma unroll
    for (int q = 0; q < 2; ++q) {
        const int idx = wv * 2 + q;
        const int tl  = idx >> 2;           // 0..3
        const int k4  = idx & 3;            // 0..3
        const s16x8 fr = *(const s16x8*)&lt[tl * 16 + l15][k4 * 32 + l4 * 8];
        F[((size_t)(blockIdx.x * 4 + tl) * 4 + k4) * 64 + lane] = fr;
    }
}

// ---------------------------------------------------------------------------
// Kernel B v4 (fused single pass): 1024 blocks x 1024 thr, block = one 16-row
// tile x 4096 cols, wave = 256-col strip. exp stash -> f16 LDS (XOR-swizzled).
// Write phase: wave w writes output row w as 16 x 1KB CONTIGUOUS NT stores.
// R11 fix: swizzle applied on the READ ADDRESS only; store goes to the
// LOGICAL column (lane*4) — R10 double-applied it (read addr AND store col).
// ---------------------------------------------------------------------------
#define LOADT(dst, t) { const s16x8* _p = base + (size_t)(t) * 256;            \
    dst[0] = _p[0]; dst[1] = _p[64]; dst[2] = _p[128]; dst[3] = _p[192]; }

#define COMPT(src, t) { f32x4 _a = (f32x4){0.f, 0.f, 0.f, 0.f};                \
    _a = __builtin_amdgcn_mfma_f32_16x16x32_bf16(src[0], rfrag[0], _a, 0,0,0); \
    _a = __builtin_amdgcn_mfma_f32_16x16x32_bf16(src[1], rfrag[1], _a, 0,0,0); \
    _a = __builtin_amdgcn_mfma_f32_16x16x32_bf16(src[2], rfrag[2], _a, 0,0,0); \
    _a = __builtin_amdgcn_mfma_f32_16x16x32_bf16(src[3], rfrag[3], _a, 0,0,0); \
    const float _e0 = __expf(_a[0]), _e1 = __expf(_a[1]);                      \
    const float _e2 = __expf(_a[2]), _e3 = __expf(_a[3]);                      \
    rs += (_e0 + _e1) + (_e2 + _e3);                                           \
    const __half2 _h01 = __floats2half2_rn(_e0, _e1);                          \
    const __half2 _h23 = __floats2half2_rn(_e2, _e3);                          \
    unsigned _byte = (unsigned)(l15 * 8192 + cg * 512 + (t) * 32 + l4 * 8);    \
    _byte ^= (unsigned)(l15 << 4);                                             \
    *(uint2*)(lsbase + _byte) =                                                \
        make_uint2(*(const unsigned*)&_h01, *(const unsigned*)&_h23); }

__global__ __launch_bounds__(1024)
void gram_fused_kernel(const s16x8* __restrict__ F, float* __restrict__ out)
{
    __shared__ unsigned short lsE[16][4096];    // f16 stash, 128 KB, swizzled
    __shared__ float lsum[16][16];

    const int tid  = threadIdx.x;
    const int lane = tid & 63;
    const int cg   = tid >> 6;          // col strip 0..15 (256 cols)
    const int l15  = lane & 15;
    const int l4   = lane >> 4;
    char* lsbase = (char*)&lsE[0][0];

    // XCD swizzle (bijective on 1024): 128 contiguous row-tiles per XCD
    const int u    = ((blockIdx.x & 7) << 7) | (blockIdx.x >> 3);
    const int b    = u >> 8;
    const int tr   = u & 255;
    const s16x8* Fb = F + (size_t)b * FRAG_PER_B;

    s16x8 rfrag[4];
#pragma unroll
    for (int ks = 0; ks < 4; ++ks) rfrag[ks] = Fb[((size_t)tr * 4 + ks) * 64 + lane];

    const s16x8* base = Fb + (size_t)(cg * 16) * 256 + lane;

    float rs = 0.f;
    s16x8 cA[4], cB[4], cC[4];
    LOADT(cA, 0)
    LOADT(cB, 1)
    LOADT(cC, 2)
#pragma unroll
    for (int i = 0; i < 6; ++i) {
        const int t = i * 3;
        { COMPT(cA, t)           if (t + 3 < 16) LOADT(cA, t + 3) }
        if (t + 1 < 16) { COMPT(cB, t + 1) if (t + 4 < 16) LOADT(cB, t + 4) }
        if (t + 2 < 16) { COMPT(cC, t + 2) if (t + 5 < 16) LOADT(cC, t + 5) }
    }

    // rowsum partials: l4 groups hold partial sums of row l15
    rs += __shfl_xor(rs, 16);
    rs += __shfl_xor(rs, 32);
    if (lane < 16) lsum[lane][cg] = rs;
    __syncthreads();                     // lsE + lsum complete

    // write phase: wave cg owns output row cg of this tile
    float s = 0.f;
#pragma unroll
    for (int w = 0; w < 16; ++w) s += lsum[cg][w];
    const float rv = 1.f / s;

    float* ob = out + ((size_t)b * SEQ + tr * 16 + cg) * SEQ;
    const unsigned swz = (unsigned)(cg << 4);
#pragma unroll
    for (int it = 0; it < 16; ++it) {
        // read addr un-swizzles -> data fetched is LOGICAL col-chunk lane*4
        const unsigned sbyte = (unsigned)(cg * 8192 + it * 512 + lane * 8) ^ swz;
        const uint2 d = *(const uint2*)(lsbase + sbyte);
        const float2 f01 = __half22float2(*(const __half2*)&d.x);
        const float2 f23 = __half22float2(*(const __half2*)&d.y);
        f32x4 pv;
        pv[0] = f01.x * rv;
        pv[1] = f01.y * rv;
        pv[2] = f23.x * rv;
        pv[3] = f23.y * rv;
        __builtin_nontemporal_store(pv, (f32x4*)(ob + it * 256 + lane * 4));
    }
}

extern "C" void kernel_launch(void* const* d_in, const int* in_sizes, int n_in,
                              void* d_out, int out_size, void* d_ws, size_t ws_size,
                              hipStream_t stream)
{
    const float* query = (const float*)d_in[0];
    // d_in[1] = key (unused by the forward)
    const float* Wq    = (const float*)d_in[2];
    const float* bq    = (const float*)d_in[3];
    const float* wt    = (const float*)d_in[4];
    float* out = (float*)d_out;
    s16x8* F  = (s16x8*)d_ws;                               // 4 MiB
    s16x8* WF = (s16x8*)((char*)d_ws + (size_t)4 * 1024 * 1024);  // 256 KiB

    wq_frag_kernel<<<dim3(256), dim3(64), 0, stream>>>(Wq, wt, WF);
    ctx_norm_kernel<<<dim3(ROWS_TOTAL / 64), dim3(512), 0, stream>>>(query, WF, bq, wt, F);
    gram_fused_kernel<<<dim3(BATCH * TPB), dim3(1024), 0, stream>>>(F, out);
}